// Round 5
// baseline (716.140 us; speedup 1.0000x reference)
//
#include <hip/hip_runtime.h>

#define HH 1024
#define WW 1024
#define RPT 8            // output rows per thread
#define NR (RPT + 10)    // input rows streamed
#define WAVES 4

__global__ __launch_bounds__(256, 5) void diamond_kernel(const float* __restrict__ in,
                                                         float* __restrict__ out) {
    const int tj = threadIdx.x;          // lane 0..63, owns cols j0..j0+3
    const int ty = threadIdx.y;          // wave 0..3
    const int b  = blockIdx.z;
    const int j0 = (blockIdx.x * 64 + tj) * 4;
    const int i0 = blockIdx.y * (WAVES * RPT) + ty * RPT;
    const float* __restrict__ src = in  + (size_t)b * HH * WW;
    float*       __restrict__ dst = out + (size_t)b * HH * WW;

    const float EV[6] = {1.0f,
                         0.36787944117144233f,   // e^-1
                         0.1353352832366127f,    // e^-2
                         0.049787068367863944f,  // e^-3
                         0.018315638888734179f,  // e^-4
                         0.006737946999085467f}; // e^-5

    float acc[RPT][4];
#pragma unroll
    for (int m = 0; m < RPT; ++m)
#pragma unroll
        for (int p = 0; p < 4; ++p) acc[m][p] = 0.0f;

#pragma unroll
    for (int rr = 0; rr < NR; ++rr) {
        const int ri = (i0 + rr - 5) & (HH - 1);
        const float* row = src + (size_t)ri * WW;

        // 20 contiguous floats covering cols j0-8 .. j0+11 (4-aligned chunks,
        // 1024 % 4 == 0 so & (WW-1) wraps whole chunks, 16B-aligned)
        float4 c[5];
#pragma unroll
        for (int t = 0; t < 5; ++t) {
            const int cb = (j0 - 8 + 4 * t) & (WW - 1);
            c[t] = *reinterpret_cast<const float4*>(row + cb);
        }
        float s[20];
#pragma unroll
        for (int t = 0; t < 5; ++t) {
            s[4 * t + 0] = c[t].x;
            s[4 * t + 1] = c[t].y;
            s[4 * t + 2] = c[t].z;
            s[4 * t + 3] = c[t].w;
        }

        // level-k horizontal sums consumed on the fly:
        // level k feeds output rows m = rr-k and m = rr-10+k with weight EV[5-k]
        float Hc[4];
#pragma unroll
        for (int p = 0; p < 4; ++p) Hc[p] = s[8 + p];
        {   // k = 0, a = 5
            const int m1 = rr - 10, m2 = rr;
            if (m1 >= 0 && m1 < RPT)
#pragma unroll
                for (int p = 0; p < 4; ++p) acc[m1][p] = fmaf(EV[5], Hc[p], acc[m1][p]);
            if (m2 >= 0 && m2 < RPT)
#pragma unroll
                for (int p = 0; p < 4; ++p) acc[m2][p] = fmaf(EV[5], Hc[p], acc[m2][p]);
        }
#pragma unroll
        for (int k = 1; k <= 4; ++k) {
#pragma unroll
            for (int p = 0; p < 4; ++p)
                Hc[p] = fmaf(EV[k], s[8 + p - k] + s[8 + p + k], Hc[p]);
            const int a = 5 - k;
            const int m1 = rr - 10 + k, m2 = rr - k;
            if (m1 >= 0 && m1 < RPT)
#pragma unroll
                for (int p = 0; p < 4; ++p) acc[m1][p] = fmaf(EV[a], Hc[p], acc[m1][p]);
            if (m2 >= 0 && m2 < RPT && m2 != m1)
#pragma unroll
                for (int p = 0; p < 4; ++p) acc[m2][p] = fmaf(EV[a], Hc[p], acc[m2][p]);
        }
        {   // k = 5 → center row (a = 0): weight 1, subtract the self term
#pragma unroll
            for (int p = 0; p < 4; ++p)
                Hc[p] = fmaf(EV[5], s[8 + p - 5] + s[8 + p + 5], Hc[p]);
            const int m = rr - 5;
            if (m >= 0 && m < RPT)
#pragma unroll
                for (int p = 0; p < 4; ++p) acc[m][p] += Hc[p] - s[8 + p];
        }
    }

#pragma unroll
    for (int m = 0; m < RPT; ++m) {
        float4 v = make_float4(acc[m][0], acc[m][1], acc[m][2], acc[m][3]);
        *reinterpret_cast<float4*>(dst + (size_t)(i0 + m) * WW + j0) = v;
    }
}

extern "C" void kernel_launch(void* const* d_in, const int* in_sizes, int n_in,
                              void* d_out, int out_size, void* d_ws, size_t ws_size,
                              hipStream_t stream) {
    const float* in  = (const float*)d_in[0];
    float*       out = (float*)d_out;
    const int B = in_sizes[0] / (HH * WW);   // 64
    dim3 block(64, WAVES, 1);
    dim3 grid(WW / 256, HH / (WAVES * RPT), B);
    hipLaunchKernelGGL(diamond_kernel, grid, block, 0, stream, in, out);
}

// Round 6
// 117.863 us; speedup vs baseline: 6.0761x; 6.0761x over previous
//
#include <hip/hip_runtime.h>

#define HH 1024
#define WW 1024
#define BM 32            // output rows per block
#define BN 256           // output cols per block
#define RPT 8            // output rows per thread (BM / WAVES)
#define WAVES 4
#define TROWS (BM + 10)  // 42 staged input rows
#define TCOLS 272        // staged floats per row (256 + 8 left + 8 right)
#define TFLOATS (TROWS * TCOLS)        // 11424
#define NSTG ((TFLOATS + 255) / 256)   // 45 staging instructions (1 KB each)
#define LDSF (NSTG * 256)              // 11520 floats of LDS (padded)

typedef __attribute__((address_space(1))) const float gfloat;
typedef __attribute__((address_space(3))) float sfloat;

__global__ __launch_bounds__(256) void diamond_kernel(const float* __restrict__ in,
                                                      float* __restrict__ out) {
    __shared__ __attribute__((aligned(16))) float tile[LDSF];

    const int tj  = threadIdx.x;                 // lane 0..63
    const int ty  = threadIdx.y;                 // wave 0..3
    const int b   = blockIdx.z;
    const int J0  = blockIdx.x * BN;             // block's first output col
    const int i0b = blockIdx.y * BM;             // block's first output row
    const float* __restrict__ src = in  + (size_t)b * HH * WW;
    float*       __restrict__ dst = out + (size_t)b * HH * WW;

    // ---- stage (i0b-5 .. i0b+BM+4) x (J0-8 .. J0+263) into LDS, zero VGPR cost.
    // tile row r holds global row (i0b + r - 5); tile col c holds global col
    // (J0 - 8 + c). Instruction I stages LDS floats [I*256, I*256+256):
    // LDS dest = uniform base + lane*16; global src is per-lane (wraps).
#pragma unroll
    for (int n = 0; n < 12; ++n) {
        const int I = ty + 4 * n;                // wave-uniform predicate
        if (I < NSTG) {
            const int f = I * 256 + 4 * tj;      // flat float index in tile
            const int r = f / TCOLS;
            const int c = f - r * TCOLS;
            const int gr = (i0b + r - 5) & (HH - 1);
            const int gc = (J0 - 8 + c) & (WW - 1);   // c%4==0 -> 16B aligned
            __builtin_amdgcn_global_load_lds((gfloat*)(src + (size_t)gr * WW + gc),
                                             (sfloat*)&tile[I * 256], 16, 0, 0);
        }
    }
    __syncthreads();   // drains vmcnt(0): all DMAs landed, visible to all waves

    const float EV[6] = {1.0f,
                         0.36787944117144233f,   // e^-1
                         0.1353352832366127f,    // e^-2
                         0.049787068367863944f,  // e^-3
                         0.018315638888734179f,  // e^-4
                         0.006737946999085467f}; // e^-5

    float acc[RPT][4];
#pragma unroll
    for (int m = 0; m < RPT; ++m)
#pragma unroll
        for (int p = 0; p < 4; ++p) acc[m][p] = 0.0f;

    const int base_r = ty * RPT;   // wave's first tile row (= its first out row)

#pragma unroll
    for (int rr = 0; rr < RPT + 10; ++rr) {
        const float* trow = &tile[(base_r + rr) * TCOLS + 4 * tj];

        // 20-float window: tile cols 4tj .. 4tj+19  (s[8+p] = output col p)
        float s[20];
#pragma unroll
        for (int t = 0; t < 5; ++t) {
            float4 v = *reinterpret_cast<const float4*>(trow + 4 * t);
            s[4 * t + 0] = v.x; s[4 * t + 1] = v.y;
            s[4 * t + 2] = v.z; s[4 * t + 3] = v.w;
        }

        // level-k horizontal sums consumed on the fly:
        // level k feeds output rows m = rr-k and m = rr-10+k with weight EV[5-k]
        float Hc[4];
#pragma unroll
        for (int p = 0; p < 4; ++p) Hc[p] = s[8 + p];
        {   // k = 0, a = 5
            const int m1 = rr - 10, m2 = rr;
            if (m1 >= 0 && m1 < RPT)
#pragma unroll
                for (int p = 0; p < 4; ++p) acc[m1][p] = fmaf(EV[5], Hc[p], acc[m1][p]);
            if (m2 >= 0 && m2 < RPT)
#pragma unroll
                for (int p = 0; p < 4; ++p) acc[m2][p] = fmaf(EV[5], Hc[p], acc[m2][p]);
        }
#pragma unroll
        for (int k = 1; k <= 4; ++k) {
#pragma unroll
            for (int p = 0; p < 4; ++p)
                Hc[p] = fmaf(EV[k], s[8 + p - k] + s[8 + p + k], Hc[p]);
            const int a = 5 - k;
            const int m1 = rr - 10 + k, m2 = rr - k;
            if (m1 >= 0 && m1 < RPT)
#pragma unroll
                for (int p = 0; p < 4; ++p) acc[m1][p] = fmaf(EV[a], Hc[p], acc[m1][p]);
            if (m2 >= 0 && m2 < RPT && m2 != m1)
#pragma unroll
                for (int p = 0; p < 4; ++p) acc[m2][p] = fmaf(EV[a], Hc[p], acc[m2][p]);
        }
        {   // k = 5 -> center row (a = 0): weight 1, subtract the self term
#pragma unroll
            for (int p = 0; p < 4; ++p)
                Hc[p] = fmaf(EV[5], s[8 + p - 5] + s[8 + p + 5], Hc[p]);
            const int m = rr - 5;
            if (m >= 0 && m < RPT)
#pragma unroll
                for (int p = 0; p < 4; ++p) acc[m][p] += Hc[p] - s[8 + p];
        }
    }

#pragma unroll
    for (int m = 0; m < RPT; ++m) {
        float4 v = make_float4(acc[m][0], acc[m][1], acc[m][2], acc[m][3]);
        *reinterpret_cast<float4*>(dst + (size_t)(i0b + base_r + m) * WW + J0 + 4 * tj) = v;
    }
}

extern "C" void kernel_launch(void* const* d_in, const int* in_sizes, int n_in,
                              void* d_out, int out_size, void* d_ws, size_t ws_size,
                              hipStream_t stream) {
    const float* in  = (const float*)d_in[0];
    float*       out = (float*)d_out;
    const int B = in_sizes[0] / (HH * WW);   // 64
    dim3 block(64, WAVES, 1);
    dim3 grid(WW / BN, HH / BM, B);
    hipLaunchKernelGGL(diamond_kernel, grid, block, 0, stream, in, out);
}

// Round 8
// 97.464 us; speedup vs baseline: 7.3477x; 1.2093x over previous
//
#include <hip/hip_runtime.h>

#define HH 1024
#define WW 1024
#define BM 32            // output rows per block
#define BN 256           // output cols per block
#define RPT 8            // output rows per thread (BM / WAVES)
#define WAVES 4
#define TROWS (BM + 10)  // 42 staged input rows
#define TCOLS 272        // staged floats per row (256 + 8 left + 8 right)
#define TFLOATS (TROWS * TCOLS)        // 11424
#define NSTG ((TFLOATS + 255) / 256)   // 45 staging instructions (1 KB each)
#define LDSF (NSTG * 256)              // 11520 floats of LDS (padded)
#define NXCD 8
#define GX (WW / BN)     // 4
#define GY (HH / BM)     // 32

typedef __attribute__((address_space(1))) const float gfloat;
typedef __attribute__((address_space(3))) float sfloat;
typedef float vfloat4 __attribute__((ext_vector_type(4)));   // native vec for nontemporal

__global__ __launch_bounds__(256) void diamond_kernel(const float* __restrict__ in,
                                                      float* __restrict__ out,
                                                      int nblocks) {
    __shared__ __attribute__((aligned(16))) float tile[LDSF];

    // XCD-aware swizzle: dispatcher assigns wgid % 8 -> XCD. Remap so each XCD
    // owns a contiguous range of work items (8 whole batch-images), making
    // both row- and col-halo fetches L2-local. Bijective: nblocks % 8 == 0.
    const int wgid = blockIdx.x;
    const int swz  = (wgid % NXCD) * (nblocks / NXCD) + wgid / NXCD;
    const int b    = swz / (GX * GY);
    const int rem  = swz % (GX * GY);
    const int gy   = rem / GX;
    const int gx   = rem % GX;

    const int tj  = threadIdx.x;                 // lane 0..63
    const int ty  = threadIdx.y;                 // wave 0..3
    const int J0  = gx * BN;                     // block's first output col
    const int i0b = gy * BM;                     // block's first output row
    const float* __restrict__ src = in  + (size_t)b * HH * WW;
    float*       __restrict__ dst = out + (size_t)b * HH * WW;

    // ---- stage (i0b-5 .. i0b+BM+4) x (J0-8 .. J0+263) into LDS, zero VGPR cost.
    // tile row r holds global row (i0b + r - 5); tile col c holds global col
    // (J0 - 8 + c). Instruction I stages LDS floats [I*256, I*256+256):
    // LDS dest = uniform base + lane*16; global src is per-lane (wraps).
#pragma unroll
    for (int n = 0; n < 12; ++n) {
        const int I = ty + 4 * n;                // wave-uniform predicate
        if (I < NSTG) {
            const int f = I * 256 + 4 * tj;      // flat float index in tile
            const int r = f / TCOLS;
            const int c = f - r * TCOLS;
            const int gr = (i0b + r - 5) & (HH - 1);
            const int gc = (J0 - 8 + c) & (WW - 1);   // c%4==0 -> 16B aligned
            __builtin_amdgcn_global_load_lds((gfloat*)(src + (size_t)gr * WW + gc),
                                             (sfloat*)&tile[I * 256], 16, 0, 0);
        }
    }
    __syncthreads();   // drains vmcnt(0): all DMAs landed, visible to all waves

    const float EV[6] = {1.0f,
                         0.36787944117144233f,   // e^-1
                         0.1353352832366127f,    // e^-2
                         0.049787068367863944f,  // e^-3
                         0.018315638888734179f,  // e^-4
                         0.006737946999085467f}; // e^-5

    float acc[RPT][4];
#pragma unroll
    for (int m = 0; m < RPT; ++m)
#pragma unroll
        for (int p = 0; p < 4; ++p) acc[m][p] = 0.0f;

    const int base_r = ty * RPT;   // wave's first tile row (= its first out row)

#pragma unroll
    for (int rr = 0; rr < RPT + 10; ++rr) {
        const float* trow = &tile[(base_r + rr) * TCOLS + 4 * tj];

        // 20-float window: tile cols 4tj .. 4tj+19  (s[8+p] = output col p)
        float s[20];
#pragma unroll
        for (int t = 0; t < 5; ++t) {
            float4 v = *reinterpret_cast<const float4*>(trow + 4 * t);
            s[4 * t + 0] = v.x; s[4 * t + 1] = v.y;
            s[4 * t + 2] = v.z; s[4 * t + 3] = v.w;
        }

        // level-k horizontal sums consumed on the fly:
        // level k feeds output rows m = rr-k and m = rr-10+k with weight EV[5-k]
        float Hc[4];
#pragma unroll
        for (int p = 0; p < 4; ++p) Hc[p] = s[8 + p];
        {   // k = 0, a = 5
            const int m1 = rr - 10, m2 = rr;
            if (m1 >= 0 && m1 < RPT)
#pragma unroll
                for (int p = 0; p < 4; ++p) acc[m1][p] = fmaf(EV[5], Hc[p], acc[m1][p]);
            if (m2 >= 0 && m2 < RPT)
#pragma unroll
                for (int p = 0; p < 4; ++p) acc[m2][p] = fmaf(EV[5], Hc[p], acc[m2][p]);
        }
#pragma unroll
        for (int k = 1; k <= 4; ++k) {
#pragma unroll
            for (int p = 0; p < 4; ++p)
                Hc[p] = fmaf(EV[k], s[8 + p - k] + s[8 + p + k], Hc[p]);
            const int a = 5 - k;
            const int m1 = rr - 10 + k, m2 = rr - k;
            if (m1 >= 0 && m1 < RPT)
#pragma unroll
                for (int p = 0; p < 4; ++p) acc[m1][p] = fmaf(EV[a], Hc[p], acc[m1][p]);
            if (m2 >= 0 && m2 < RPT && m2 != m1)
#pragma unroll
                for (int p = 0; p < 4; ++p) acc[m2][p] = fmaf(EV[a], Hc[p], acc[m2][p]);
        }
        {   // k = 5 -> center row (a = 0): weight 1, subtract the self term
#pragma unroll
            for (int p = 0; p < 4; ++p)
                Hc[p] = fmaf(EV[5], s[8 + p - 5] + s[8 + p + 5], Hc[p]);
            const int m = rr - 5;
            if (m >= 0 && m < RPT)
#pragma unroll
                for (int p = 0; p < 4; ++p) acc[m][p] += Hc[p] - s[8 + p];
        }
    }

    // non-temporal stores: output is never re-read; keep it out of L2 so the
    // cache holds input halos for neighbor blocks instead
#pragma unroll
    for (int m = 0; m < RPT; ++m) {
        vfloat4 v = {acc[m][0], acc[m][1], acc[m][2], acc[m][3]};
        __builtin_nontemporal_store(
            v, reinterpret_cast<vfloat4*>(dst + (size_t)(i0b + base_r + m) * WW + J0 + 4 * tj));
    }
}

extern "C" void kernel_launch(void* const* d_in, const int* in_sizes, int n_in,
                              void* d_out, int out_size, void* d_ws, size_t ws_size,
                              hipStream_t stream) {
    const float* in  = (const float*)d_in[0];
    float*       out = (float*)d_out;
    const int B = in_sizes[0] / (HH * WW);   // 64
    const int nblocks = GX * GY * B;         // 8192, divisible by 8
    dim3 block(64, WAVES, 1);
    dim3 grid(nblocks, 1, 1);
    hipLaunchKernelGGL(diamond_kernel, grid, block, 0, stream, in, out, nblocks);
}